// Round 8
// baseline (45.302 us; speedup 1.0000x reference)
//
#include <hip/hip_runtime.h>
#include <stdint.h>

#define N_   64
#define C_   64
#define W_   4096
#define F_   64
#define WW_  9
#define OW_  4088        // W_ - WW_ + 1
#define WBLK 128
#define WROWS 136        // WBLK + 8 halo

typedef __bf16 bf16x8 __attribute__((ext_vector_type(8)));
typedef float  f32x4  __attribute__((ext_vector_type(4)));

__device__ __forceinline__ unsigned short f2bf(float f) {
    union { float f; uint32_t u; } v; v.f = f;
    uint32_t u = v.u;
    return (unsigned short)((u + 0x7FFFu + ((u >> 16) & 1u)) >> 16);  // RNE
}

// pack 4 floats -> 4 bf16 (two v_cvt_pk_bf16_f32, RNE)
__device__ __forceinline__ uint2 pk4(float a, float b, float c, float d) {
    uint2 r;
    asm volatile("v_cvt_pk_bf16_f32 %0, %1, %2" : "=v"(r.x) : "v"(a), "v"(b));
    asm volatile("v_cvt_pk_bf16_f32 %0, %1, %2" : "=v"(r.y) : "v"(c), "v"(d));
    return r;
}

// filt fp32 [F][C][WW] -> filtB bf16, fragment-major [t][m][uu][lane][8j]
//   f = uu*16 + (lane&15),  c = m*32 + (lane>>4)*8 + j
// Each B-fragment load in the main kernel is ONE contiguous 1KB wave load (L2-resident).
__global__ __launch_bounds__(256) void prep_filt_k(const float* __restrict__ filt,
                                                   unsigned short* __restrict__ filtB) {
    int id = blockIdx.x * 256 + threadIdx.x;
    if (id < WW_ * F_ * C_) {
        int j    = id & 7;
        int lane = (id >> 3) & 63;
        int uu   = (id >> 9) & 3;
        int m    = (id >> 11) & 1;
        int t    = id >> 12;
        int l15  = lane & 15, lg = lane >> 4;
        int f = uu * 16 + l15;
        int c = m * 32 + lg * 8 + j;
        filtB[id] = f2bf(filt[(f * C_ + c) * WW_ + t]);
    }
}

// Block = 128 thr = 2 waves; tile = (n, 128w) x all 64f; wave = 64w x 64f.
// 4:1 MFMA:ds_read (16 MFMA per 4 A-reads per k-step), B prefetched depth-1.
// (128,3): VGPR cap ~170 (budget ~130, no spill), 6 blocks/CU via LDS.
__global__ __launch_bounds__(128, 3) void conv_k(const float* __restrict__ x,
                                                 const unsigned short* __restrict__ filtB,
                                                 const float* __restrict__ bias,
                                                 float* __restrict__ out) {
    __shared__ unsigned short xs[WROWS * 64];   // 17408 B, swizzled rows of 128B

    const int tid  = threadIdx.x;
    const int lane = tid & 63;
    const int wv   = tid >> 6;                  // 0..1
    const int n    = blockIdx.y;
    const int w0   = blockIdx.x * WBLK;
    const int l15  = lane & 15;
    const int lg   = lane >> 4;

    // ---- staging: x[c][w0..w0+135] f32 -> xs[w][c] bf16, chunk-XOR swizzled ----
    // Main 128 w: thread owns w-quad (tid&31)*4, c rows (tid>>5)*4 + 16i, i=0..3.
    {
        const int wq    = (tid & 31) << 2;
        const int cbase = (tid >> 5) << 2;      // 0,4,8,12
        #pragma unroll
        for (int i = 0; i < 4; ++i) {
            const int c4 = cbase + (i << 4);
            const float* xb = x + ((size_t)(n * C_ + c4)) * W_ + w0 + wq;
            float4 r0 = *reinterpret_cast<const float4*>(xb);
            float4 r1 = *reinterpret_cast<const float4*>(xb + W_);
            float4 r2 = *reinterpret_cast<const float4*>(xb + 2 * W_);
            float4 r3 = *reinterpret_cast<const float4*>(xb + 3 * W_);
            const int cg = c4 >> 3;
            const int cs = c4 & 7;              // 0 or 4
            const float* p0 = &r0.x; const float* p1 = &r1.x;
            const float* p2 = &r2.x; const float* p3 = &r3.x;
            #pragma unroll
            for (int jj = 0; jj < 4; ++jj) {
                int w = wq + jj;
                uint2 u2 = pk4(p0[jj], p1[jj], p2[jj], p3[jj]);
                *reinterpret_cast<uint2*>(&xs[w * 64 + ((cg ^ (w & 7)) << 3) + cs]) = u2;
            }
        }
        // Halo w = 128..135 (8 w x 64 c), threads 0..31, guarded (last block only).
        if (tid < 32) {
            const int hc4 = (tid & 15) << 2;
            const int hwl = 128 + ((tid >> 4) << 2);
            const int hcg = hc4 >> 3;
            const int hcs = hc4 & 7;
            #pragma unroll
            for (int jj = 0; jj < 4; ++jj) {
                int w  = hwl + jj;
                int gw = w0 + w;
                float a0 = 0.f, a1 = 0.f, a2 = 0.f, a3 = 0.f;
                if (gw < W_) {
                    const float* hp = x + ((size_t)(n * C_ + hc4)) * W_ + gw;
                    a0 = hp[0];
                    a1 = hp[(size_t)W_];
                    a2 = hp[(size_t)2 * W_];
                    a3 = hp[(size_t)3 * W_];
                }
                uint2 u2 = pk4(a0, a1, a2, a3);
                *reinterpret_cast<uint2*>(&xs[w * 64 + ((hcg ^ (w & 7)) << 3) + hcs]) = u2;
            }
        }
    }
    __syncthreads();

    // ---- compute: wave = 64w x 64f; K = 9 taps x 2 c-halves ----
    const int wvb = wv << 6;                    // wave w-base (0 or 64)
    const unsigned short* Bb = filtB + lane * 8;

    float bv[4];
    #pragma unroll
    for (int uu = 0; uu < 4; ++uu)
        bv[uu] = 64.0f * bias[uu * 16 + l15];   // ref adds bias once per channel -> C*bias

    f32x4 acc[4][4];                            // [s(w)][uu(f)]
    #pragma unroll
    for (int s = 0; s < 4; ++s)
        #pragma unroll
        for (int uu = 0; uu < 4; ++uu)
            acc[s][uu] = (f32x4){0.f, 0.f, 0.f, 0.f};

    bf16x8 Bc[4], Bn[4];
    #pragma unroll
    for (int u = 0; u < 4; ++u)                 // step 0 fragments
        Bc[u] = *reinterpret_cast<const bf16x8*>(Bb + (u << 9));

    #pragma unroll
    for (int t = 0; t < WW_; ++t) {
        #pragma unroll
        for (int m = 0; m < 2; ++m) {
            const int step = t * 2 + m;
            if (step < 17) {                    // prefetch next step's B frags
                #pragma unroll
                for (int u = 0; u < 4; ++u)
                    Bn[u] = *reinterpret_cast<const bf16x8*>(Bb + (((step + 1) * 4 + u) << 9));
            }
            bf16x8 a[4];
            #pragma unroll
            for (int s = 0; s < 4; ++s) {
                int row   = wvb + s * 16 + l15 + t;              // <= 135
                int chunk = ((m << 2) | lg) ^ (row & 7);
                a[s] = *reinterpret_cast<const bf16x8*>(&xs[row * 64 + chunk * 8]);
            }
            __builtin_amdgcn_s_setprio(1);
            #pragma unroll
            for (int s = 0; s < 4; ++s)
                #pragma unroll
                for (int u = 0; u < 4; ++u)
                    acc[s][u] = __builtin_amdgcn_mfma_f32_16x16x32_bf16(a[s], Bc[u], acc[s][u], 0, 0, 0);
            __builtin_amdgcn_s_setprio(0);
            #pragma unroll
            for (int u = 0; u < 4; ++u) Bc[u] = Bn[u];   // SSA-renamed by unroll
        }
    }

    // ---- epilogue: D col=f=lane&15, row=w=(lane>>4)*4+reg ; fused bias; float4 stores ----
    #pragma unroll
    for (int uu = 0; uu < 4; ++uu) {
        const int f = uu * 16 + l15;
        #pragma unroll
        for (int s = 0; s < 4; ++s) {
            int wg = w0 + wvb + s * 16 + lg * 4;
            if (wg < OW_) {                    // wg%4==0, OW_%4==0 -> whole float4 in-range
                float4 o;
                o.x = acc[s][uu][0] + bv[uu];
                o.y = acc[s][uu][1] + bv[uu];
                o.z = acc[s][uu][2] + bv[uu];
                o.w = acc[s][uu][3] + bv[uu];
                *reinterpret_cast<float4*>(out + ((size_t)(n * F_ + f) * OW_ + wg)) = o;
            }
        }
    }
}

extern "C" void kernel_launch(void* const* d_in, const int* in_sizes, int n_in,
                              void* d_out, int out_size, void* d_ws, size_t ws_size,
                              hipStream_t stream) {
    const float* x    = (const float*)d_in[0];
    const float* filt = (const float*)d_in[1];
    const float* bias = (const float*)d_in[2];
    float* out        = (float*)d_out;

    unsigned short* filtB = (unsigned short*)d_ws;   // 9*64*64 bf16 = 73728 B

    prep_filt_k<<<(WW_ * F_ * C_ + 255) / 256, 256, 0, stream>>>(filt, filtB);

    dim3 grid(W_ / WBLK, N_);   // 32 x 64 = 2048 blocks of 128 threads
    conv_k<<<grid, 128, 0, stream>>>(x, filtB, bias, out);
}